// Round 1
// baseline (699.221 us; speedup 1.0000x reference)
//
#include <hip/hip_runtime.h>
#include <math.h>

// ---------------------------------------------------------------------------
// Hyperbolic GCN forward, fully collapsed + wave-specialized fusion:
//  - logmap0(proj(expmap0(u))) == u ; bias chain is affine (At,Au per row)
//  - ALL GEMMs on matrix cores via split-bf16 (x = hi + lo, 3 MFMA passes).
//  - W (hi+lo, 64 KB) staged in LDS once per block; 512 persistent blocks.
//  - FUSION (this round): hist atomics ride as wave 4 of mfma(loga1) —
//    hist_k standalone was atomic-throughput bound (56 MB write-through,
//    VALU 0.3%), pure dead time; CSR fill rides as wave 4 of mfma(h1);
//    batch_head's s3 half rides as waves 4-5 of mfma(h2). Blocks can't be
//    role-split (64 KB LDS is reserved per block either way), but an extra
//    wave costs nothing at 2 blocks/CU.
//  - Lx2 now packed bf16 (only consumer is the head gather): halves
//    seg_x2 writes and head fetch.
// ---------------------------------------------------------------------------

typedef unsigned short ushort_t;
typedef __attribute__((ext_vector_type(8))) short short8;
typedef __attribute__((ext_vector_type(4))) float f32x4;
typedef __attribute__((ext_vector_type(4))) unsigned short u16x4;

__device__ __forceinline__ float wsum(float x){
  x += __shfl_xor(x, 32);
  x += __shfl_xor(x, 16);
  x += __shfl_xor(x, 8);
  x += __shfl_xor(x, 4);
  x += __shfl_xor(x, 2);
  x += __shfl_xor(x, 1);
  return x;
}

__device__ __forceinline__ void get_c(const float* rc, float& K, float& sK){
  float c = log1pf(expf(rc[0])) + 1e-5f;   // softplus(raw_c) + 1e-5
  K  = 1.0f / c;
  sK = sqrtf(K);
}

__device__ __forceinline__ float sinhx_over_x(float x){
  if (x > 1e-3f){
    float e  = __expf(x);
    float em = __builtin_amdgcn_rcpf(e);
    return 0.5f*(e - em) * __builtin_amdgcn_rcpf(x);
  }
  return 1.0f + x*x*(1.0f/6.0f);
}

__device__ __forceinline__ float facosh(float x){   // x >= 1+1e-7
  return __logf(x + sqrtf(fmaxf(fmaf(x, x, -1.0f), 0.0f)));
}

__device__ __forceinline__ ushort_t bf16_rne(float x){
  unsigned int u = __float_as_uint(x);
  u += 0x7fffu + ((u >> 16) & 1u);
  return (ushort_t)(u >> 16);
}
__device__ __forceinline__ float bf2f(ushort_t h){
  return __uint_as_float(((unsigned int)h) << 16);
}
__device__ __forceinline__ unsigned int pack_bf16(float x, float y){
  unsigned int bx = __float_as_uint(x);
  unsigned int by = __float_as_uint(y);
  bx = (bx + 0x7fffu + ((bx >> 16) & 1u)) >> 16;
  by = (by + 0x7fffu + ((by >> 16) & 1u)) & 0xffff0000u;
  return bx | by;
}
__device__ __forceinline__ float bf_lo(unsigned int p){ return __uint_as_float(p << 16); }
__device__ __forceinline__ float bf_hi(unsigned int p){ return __uint_as_float(p & 0xffff0000u); }

// Chain scalars: out_j = At*t_j + Au*u_j == logmap0(mobius_add(exp-chain)).
__device__ __forceinline__ void chain_scalars(float tt, float tu, float uu,
                                              float K, float sK,
                                              float& At, float& Au){
  float xn  = fmaxf(sqrtf(tt), 1e-15f);
  float th  = xn / sK;
  float f   = sinhx_over_x(th);
  float pn2 = f*f*tt;
  float p0  = sqrtf(fmaxf(K + pn2, 1e-7f));
  float S_yu = f * tu;
  float yn  = fmaxf(sqrtf(pn2), 1e-15f);
  float inv_yn = __builtin_amdgcn_rcpf(yn);
  float alpha = S_yu * inv_yn / sK;
  float coef  = alpha * (sK - p0);
  float cy  = coef * inv_yn;
  float cyf = cy * f;
  float pdw  = S_yu - cy*pn2;
  float spsq = uu - 2.f*cy*S_yu + cy*cy*pn2;
  float w0 = pdw / fmaxf(p0, 1e-7f);
  float md = spsq - w0*w0;
  float normu = fminf(sqrtf(fmaxf(md, 1e-7f)), 1e6f);
  float th2 = fmaxf(normu / sK, 1e-15f);
  float e  = __expf(th2);
  float em = __builtin_amdgcn_rcpf(e);
  float ch = 0.5f*(e + em);
  float g  = (th2 > 1e-3f) ? 0.5f*(e - em)*__builtin_amdgcn_rcpf(th2)
                           : 1.0f + th2*th2*(1.0f/6.0f);
  float rn2 = ch*ch*pn2 + 2.f*ch*g*pdw + g*g*spsq;
  float r0 = sqrtf(fmaxf(K + rn2, 1e-7f));
  float ynf = fmaxf(sqrtf(rn2), 1e-15f);
  float thf = fmaxf(r0/sK, 1.f+1e-7f);
  float rf = sK * facosh(thf) * __builtin_amdgcn_rcpf(ynf);
  At = rf*(ch*f - g*cyf);
  Au = rf*g;
}

// ---------- stage A: split A1[:,1:] into bf16 hi/lo (4 elems/thread) --------
__global__ __launch_bounds__(256) void stage_a(const float* __restrict__ A1,
                                               ushort_t* __restrict__ Lhi,
                                               ushort_t* __restrict__ Llo,
                                               int* __restrict__ cnt,
                                               const float* __restrict__ b0,
                                               const float* __restrict__ b1,
                                               const float* __restrict__ b2,
                                               float* __restrict__ uu3, int n){
  size_t i4 = (size_t)blockIdx.x * 256 + threadIdx.x;
  size_t tot4 = (size_t)n * 32;
  if (i4 < tot4){
    size_t row = i4 >> 5; int j0 = (int)(i4 & 31) * 4;
    const float* s = A1 + row*129 + 1 + j0;
    float v0 = s[0], v1 = s[1], v2 = s[2], v3 = s[3];
    ushort_t h0 = bf16_rne(v0), h1 = bf16_rne(v1), h2 = bf16_rne(v2), h3 = bf16_rne(v3);
    u16x4 hh = {h0, h1, h2, h3};
    u16x4 ll = {bf16_rne(v0 - bf2f(h0)), bf16_rne(v1 - bf2f(h1)),
                bf16_rne(v2 - bf2f(h2)), bf16_rne(v3 - bf2f(h3))};
    *(u16x4*)&Lhi[i4*4] = hh;
    *(u16x4*)&Llo[i4*4] = ll;
  }
  if (i4 < (size_t)n) cnt[i4] = 0;
  if (blockIdx.x == 0 && threadIdx.x < 64){
    int lane = threadIdx.x;
    const float* bs[3] = {b0, b1, b2};
    for (int k = 0; k < 3; ++k){
      float x = lane ? bs[k][2*lane] : 0.0f;
      float y = bs[k][2*lane+1];
      float s = wsum(x*x + y*y);
      if (lane == 0) uu3[k] = s;
    }
  }
}

// ---------- split+transpose all three 128x128 weights in one launch ---------
__global__ __launch_bounds__(256) void split_w3(const float* __restrict__ Lin1,
                                                const float* __restrict__ G1,
                                                const float* __restrict__ G2,
                                                ushort_t* __restrict__ Wb){
  int bid = blockIdx.x;           // 0..191
  int which = bid >> 6, b = bid & 63;
  const float* W = (which == 0) ? (Lin1 + 128) : (which == 1) ? (G1 + 128) : G2;
  ushort_t* Whi = Wb + (size_t)which * 2 * 16384;
  ushort_t* Wlo = Whi + 16384;
  int id = b * 256 + threadIdx.x;   // 0..16383
  int k = id >> 7, nn = id & 127;
  float v = W[(size_t)k*128 + nn];
  ushort_t h = bf16_rne(v);
  Whi[(size_t)nn*128 + k] = h;
  Wlo[(size_t)nn*128 + k] = bf16_rne(v - bf2f(h));
}

// ---------- MFMA GEMM (split-bf16 x3) + aux wave(s) -------------------------
// Waves 0-3: GEMM strips (unchanged). Wave 4 (aux=1): histogram atomics;
// wave 4 (aux=2): CSR fill scatter; waves 4-5 (aux=3): head s3 gather+dot.
// The aux waves' latency-bound / atomic-throughput-bound work overlaps the
// GEMM waves' MFMA+LDS work on the same CUs (TLP, no vmcnt interference:
// per-wave counters).
__global__ __launch_bounds__(384) void mfma_chain(const ushort_t* __restrict__ Ahi,
                                                  const ushort_t* __restrict__ Alo,
                                                  const ushort_t* __restrict__ Whi,
                                                  const ushort_t* __restrict__ Wlo,
                                                  const float* __restrict__ bias,
                                                  const float* __restrict__ uu3, int uuidx,
                                                  const float* __restrict__ raw_c,
                                                  float* __restrict__ outF,
                                                  unsigned int* __restrict__ outH,
                                                  int mode, int n, int nWaves,
                                                  int aux, int epb, int e,
                                                  const int* __restrict__ erows,
                                                  const int* __restrict__ ecols,
                                                  const float* __restrict__ evals,
                                                  int* __restrict__ cnt,
                                                  int* __restrict__ rnk,
                                                  const int* __restrict__ off,
                                                  int2* __restrict__ ecv,
                                                  const float* __restrict__ loga1,
                                                  const int* __restrict__ bidx,
                                                  const float* __restrict__ c2w,
                                                  const float* __restrict__ c2b,
                                                  const float* __restrict__ weight2,
                                                  float* __restrict__ sel3,
                                                  float* __restrict__ outTop, int Bn){
  __shared__ ushort_t Wsh[2][128*128];   // 64 KB: [0]=hi, [1]=lo, Wt[n][k]
  int tid = threadIdx.x;
  if (tid < 256){
    const uint4* gh = (const uint4*)Whi;
    const uint4* gl = (const uint4*)Wlo;
    uint4* sh = (uint4*)Wsh[0];
    uint4* sl = (uint4*)Wsh[1];
    #pragma unroll
    for (int i = 0; i < 8; ++i){ sh[tid + 256*i] = gh[tid + 256*i]; }
    #pragma unroll
    for (int i = 0; i < 8; ++i){ sl[tid + 256*i] = gl[tid + 256*i]; }
  }
  __syncthreads();

  int lane = tid & 63;
  int warp = tid >> 6;

  if (warp >= 4){
    // ----------------------- aux waves -----------------------
    if (aux == 1){
      // histogram: atomic rank assignment for this block's edge slice
      int gpl = epb >> 8;                       // int4-groups per lane
      int gbase = (blockIdx.x * epb) >> 2;
      for (int k = 0; k < gpl; ++k){
        int b4 = (gbase + k*64 + lane) * 4;
        if (b4 + 3 < e){
          int4 r = *(const int4*)&erows[b4];
          int k0 = atomicAdd(&cnt[r.x], 1);
          int k1 = atomicAdd(&cnt[r.y], 1);
          int k2 = atomicAdd(&cnt[r.z], 1);
          int k3 = atomicAdd(&cnt[r.w], 1);
          *(int4*)&rnk[b4] = make_int4(k0, k1, k2, k3);
        } else {
          for (int i = b4; i < e; ++i) rnk[i] = atomicAdd(&cnt[erows[i]], 1);
        }
      }
    } else if (aux == 2){
      // CSR fill: scatter (col,val) to off[row]+rank
      int gpl = epb >> 8;
      int gbase = (blockIdx.x * epb) >> 2;
      for (int k = 0; k < gpl; ++k){
        int b4 = (gbase + k*64 + lane) * 4;
        if (b4 + 3 < e){
          int4   r = *(const int4*)&erows[b4];
          int4   q = *(const int4*)&rnk[b4];
          int4   cc = *(const int4*)&ecols[b4];
          float4 vv = *(const float4*)&evals[b4];
          int o0 = off[r.x], o1 = off[r.y], o2 = off[r.z], o3 = off[r.w];
          ecv[o0 + q.x] = make_int2(cc.x, __float_as_int(vv.x));
          ecv[o1 + q.y] = make_int2(cc.y, __float_as_int(vv.y));
          ecv[o2 + q.z] = make_int2(cc.z, __float_as_int(vv.z));
          ecv[o3 + q.w] = make_int2(cc.w, __float_as_int(vv.w));
        } else {
          for (int i = b4; i < e; ++i)
            ecv[off[erows[i]] + rnk[i]] = make_int2(ecols[i], __float_as_int(evals[i]));
        }
      }
    } else if (aux == 3){
      // head s3: per batch, g3[d] = sum_l c2w[l]*loga1[bi[l]][d];
      // s3[t] = sum_d g3[d]*weight2[d][t] + c2b. Shfl transpose, no LDS.
      float cw = (lane < 50) ? c2w[lane] : 0.f;
      for (int q = 0; q < 4; ++q){
        int b = blockIdx.x * 8 + (warp - 4) * 4 + q;
        if (b >= Bn) break;
        int bi = (lane < 50) ? bidx[(size_t)b*50 + lane] : 0;
        float gx = 0.f, gy = 0.f;
        #pragma unroll
        for (int l = 0; l < 50; l += 5){
          int i0 = __shfl(bi, l+0), i1 = __shfl(bi, l+1), i2 = __shfl(bi, l+2);
          int i3 = __shfl(bi, l+3), i4 = __shfl(bi, l+4);
          float w0 = __shfl(cw, l+0), w1 = __shfl(cw, l+1), w2v = __shfl(cw, l+2);
          float w3 = __shfl(cw, l+3), w4 = __shfl(cw, l+4);
          float2 p0 = *(const float2*)&loga1[(size_t)i0*128 + 2*lane];
          float2 p1 = *(const float2*)&loga1[(size_t)i1*128 + 2*lane];
          float2 p2 = *(const float2*)&loga1[(size_t)i2*128 + 2*lane];
          float2 p3 = *(const float2*)&loga1[(size_t)i3*128 + 2*lane];
          float2 p4 = *(const float2*)&loga1[(size_t)i4*128 + 2*lane];
          gx = fmaf(w0, p0.x, gx); gy = fmaf(w0, p0.y, gy);
          gx = fmaf(w1, p1.x, gx); gy = fmaf(w1, p1.y, gy);
          gx = fmaf(w2v, p2.x, gx); gy = fmaf(w2v, p2.y, gy);
          gx = fmaf(w3, p3.x, gx); gy = fmaf(w3, p3.y, gy);
          gx = fmaf(w4, p4.x, gx); gy = fmaf(w4, p4.y, gy);
        }
        float s = 0.f;
        #pragma unroll 8
        for (int d = 0; d < 128; d += 2){
          float ge = __shfl(gx, d >> 1);
          float go = __shfl(gy, d >> 1);
          if (lane < 50){
            s = fmaf(ge, weight2[d*50 + lane], s);
            s = fmaf(go, weight2[(d+1)*50 + lane], s);
          }
        }
        if (lane < 50){
          float v = s + c2b[0];
          sel3[(size_t)b*50 + lane] = v;
          outTop[(size_t)Bn + (size_t)b*100 + 50 + lane] = v;
        }
      }
    }
    return;
  }

  // ----------------------- GEMM waves (unchanged) -----------------------
  int c = lane & 15, quad = lane >> 4;
  int wid = blockIdx.x * 4 + warp;
  int nStrips = (n + 15) >> 4;

  float K, sK; get_c(raw_c, K, sK);
  float uu = uu3[uuidx];
  float uv[8];
  #pragma unroll
  for (int t = 0; t < 8; ++t){
    int col = t*16 + c;
    uv[t] = (col == 0) ? 0.f : bias[col];
  }

  for (int strip = wid; strip < nStrips; strip += nWaves){
    int m0 = strip * 16;
    int ra = m0 + c; if (ra > n - 1) ra = n - 1;
    short8 ahi[4], alo[4];
    #pragma unroll
    for (int kc = 0; kc < 4; ++kc){
      size_t aoff = (size_t)ra*128 + kc*32 + quad*8;
      ahi[kc] = *(const short8*)&Ahi[aoff];
      alo[kc] = *(const short8*)&Alo[aoff];
    }

    f32x4 acc[8];
    #pragma unroll
    for (int t = 0; t < 8; ++t){
      f32x4 z = {0.f, 0.f, 0.f, 0.f};
      acc[t] = z;
      int wrow = (t*16 + c) * 128;
      #pragma unroll
      for (int kc = 0; kc < 4; ++kc){
        int woff = wrow + kc*32 + quad*8;
        short8 bhi = *(const short8*)&Wsh[0][woff];
        short8 blo = *(const short8*)&Wsh[1][woff];
        acc[t] = __builtin_amdgcn_mfma_f32_16x16x32_bf16(ahi[kc], bhi, acc[t], 0, 0, 0);
        acc[t] = __builtin_amdgcn_mfma_f32_16x16x32_bf16(ahi[kc], blo, acc[t], 0, 0, 0);
        acc[t] = __builtin_amdgcn_mfma_f32_16x16x32_bf16(alo[kc], bhi, acc[t], 0, 0, 0);
      }
    }

    if (c == 0){                     // output col 0 = time component, dropped
      f32x4 z = {0.f, 0.f, 0.f, 0.f};
      acc[0] = z;
    }
    #pragma unroll
    for (int r = 0; r < 4; ++r){
      float tt = 0.f, tu = 0.f;
      #pragma unroll
      for (int t = 0; t < 8; ++t){
        float v = acc[t][r];
        tt = fmaf(v, v, tt);
        tu = fmaf(v, uv[t], tu);
      }
      #pragma unroll
      for (int m = 1; m <= 8; m <<= 1){   // reduce across 16 lanes of the quad
        tt += __shfl_xor(tt, m);
        tu += __shfl_xor(tu, m);
      }
      float At, Au; chain_scalars(tt, tu, uu, K, sK, At, Au);
      int row = m0 + quad*4 + r;
      if (mode == 0){
        if (row < n){
          #pragma unroll
          for (int t = 0; t < 8; ++t){
            float o = fmaf(At, acc[t][r], Au*uv[t]);
            outF[(size_t)row*128 + t*16 + c] = o;
          }
        }
      } else {
        #pragma unroll
        for (int t = 0; t < 8; ++t){
          float o  = fmaf(At, acc[t][r], Au*uv[t]);
          float on = __shfl_xor(o, 1);
          if (row < n && !(c & 1))
            outH[(size_t)row*64 + t*8 + (c >> 1)] = pack_bf16(o, on);
        }
      }
    }
  }
}

// --------------------------- CSR scan --------------------------------------
#define SCAN_ITEMS 4
__global__ __launch_bounds__(256) void scan1(const int* __restrict__ cnt,
                                             int* __restrict__ off,
                                             int* __restrict__ bsum, int n){
  __shared__ int sh[256];
  int tid = threadIdx.x;
  int base = blockIdx.x * 256 * SCAN_ITEMS + tid * SCAN_ITEMS;
  int v[SCAN_ITEMS]; int s = 0;
  #pragma unroll
  for (int i = 0; i < SCAN_ITEMS; ++i){ int idx = base+i; v[i] = (idx < n) ? cnt[idx] : 0; s += v[i]; }
  sh[tid] = s; __syncthreads();
  for (int o = 1; o < 256; o <<= 1){
    int t = (tid >= o) ? sh[tid - o] : 0; __syncthreads();
    sh[tid] += t; __syncthreads();
  }
  int excl = sh[tid] - s;
  if (tid == 255) bsum[blockIdx.x] = sh[tid];
  int run = excl;
  #pragma unroll
  for (int i = 0; i < SCAN_ITEMS; ++i){ int idx = base+i; if (idx < n) off[idx] = run; run += v[i]; }
}

// parallel exclusive scan of block sums (G <= 256; G = ceil(N/1024) = 98)
__global__ __launch_bounds__(256) void scan2(int* __restrict__ bsum, int G){
  __shared__ int sh[256];
  int t = threadIdx.x;
  int v = (t < G) ? bsum[t] : 0;
  sh[t] = v; __syncthreads();
  for (int o = 1; o < 256; o <<= 1){
    int x = (t >= o) ? sh[t - o] : 0; __syncthreads();
    sh[t] += x; __syncthreads();
  }
  if (t < G) bsum[t] = sh[t] - v;
}

__global__ void scan3(int* __restrict__ off, const int* __restrict__ bsum, int n){
  int i = blockIdx.x * blockDim.x + threadIdx.x;
  if (i < n) off[i] += bsum[i / (256*SCAN_ITEMS)];
}

// --------------------------- seg-sum (bf16 table, int2 edges) ---------------
__device__ __forceinline__ float2 seg_gather_bf16(const unsigned int* __restrict__ h,
                                                  const int* __restrict__ off,
                                                  const int* __restrict__ cnt,
                                                  const int2* __restrict__ ecv,
                                                  int row, int lane){
  float ax = 0.f, ay = 0.f, bx = 0.f, by = 0.f;
  int st = off[row], deg = cnt[row];
  const unsigned int* __restrict__ hb = h + lane;   // row stride = 64 uints
  for (int b = 0; b < deg; b += 64){
    int k = b + lane;
    int cc = 0; float vv = 0.f;
    if (k < deg){ int2 e = ecv[st+k]; cc = e.x; vv = __int_as_float(e.y); }
    int m = min(64, deg - b);
    for (int j = 0; j < m; j += 8){
      int   c0=__shfl(cc,j+0), c1=__shfl(cc,j+1), c2=__shfl(cc,j+2), c3=__shfl(cc,j+3);
      int   c4=__shfl(cc,j+4), c5=__shfl(cc,j+5), c6=__shfl(cc,j+6), c7=__shfl(cc,j+7);
      float v0=__shfl(vv,j+0), v1=__shfl(vv,j+1), v2=__shfl(vv,j+2), v3=__shfl(vv,j+3);
      float v4=__shfl(vv,j+4), v5=__shfl(vv,j+5), v6=__shfl(vv,j+6), v7=__shfl(vv,j+7);
      unsigned int p0 = hb[(size_t)c0*64];
      unsigned int p1 = hb[(size_t)c1*64];
      unsigned int p2 = hb[(size_t)c2*64];
      unsigned int p3 = hb[(size_t)c3*64];
      unsigned int p4 = hb[(size_t)c4*64];
      unsigned int p5 = hb[(size_t)c5*64];
      unsigned int p6 = hb[(size_t)c6*64];
      unsigned int p7 = hb[(size_t)c7*64];
      ax = fmaf(v0, bf_lo(p0), ax); ay = fmaf(v0, bf_hi(p0), ay);
      bx = fmaf(v1, bf_lo(p1), bx); by = fmaf(v1, bf_hi(p1), by);
      ax = fmaf(v2, bf_lo(p2), ax); ay = fmaf(v2, bf_hi(p2), ay);
      bx = fmaf(v3, bf_lo(p3), bx); by = fmaf(v3, bf_hi(p3), by);
      ax = fmaf(v4, bf_lo(p4), ax); ay = fmaf(v4, bf_hi(p4), ay);
      bx = fmaf(v5, bf_lo(p5), bx); by = fmaf(v5, bf_hi(p5), by);
      ax = fmaf(v6, bf_lo(p6), ax); ay = fmaf(v6, bf_hi(p6), ay);
      bx = fmaf(v7, bf_lo(p7), bx); by = fmaf(v7, bf_hi(p7), by);
    }
  }
  return make_float2(ax + bx, ay + by);
}

// ------ seg_x1: Lx1 = (1-n)*segsum(h1) + n*loga1 -> bf16 hi/lo split --------
__global__ __launch_bounds__(256) void seg_x1(const unsigned int* __restrict__ h1,
                                              const int* __restrict__ off,
                                              const int* __restrict__ cnt,
                                              const int2* __restrict__ ecv,
                                              const float* __restrict__ loga1,
                                              const float* __restrict__ nparam,
                                              unsigned int* __restrict__ X1hi,
                                              unsigned int* __restrict__ X1lo, int n){
  int row  = (int)((blockIdx.x * blockDim.x + threadIdx.x) >> 6);
  int lane = threadIdx.x & 63;
  if (row >= n) return;
  float2 acc = seg_gather_bf16(h1, off, cnt, ecv, row, lane);
  float nv = nparam[row];
  float2 la1 = *(const float2*)&loga1[(size_t)row*128 + 2*lane];
  float ox = (1.f-nv)*acc.x + nv*la1.x;
  float oy = (1.f-nv)*acc.y + nv*la1.y;
  unsigned int hp = pack_bf16(ox, oy);
  X1hi[(size_t)row*64 + lane] = hp;
  X1lo[(size_t)row*64 + lane] = pack_bf16(ox - bf_lo(hp), oy - bf_hi(hp));
}

// ------------------- seg_x2: Lx2 = segsum(h2)  (packed bf16 out) ------------
__global__ __launch_bounds__(256) void seg_x2(const unsigned int* __restrict__ h2,
                                              const int* __restrict__ off,
                                              const int* __restrict__ cnt,
                                              const int2* __restrict__ ecv,
                                              unsigned int* __restrict__ Lx2p, int n){
  int row  = (int)((blockIdx.x * blockDim.x + threadIdx.x) >> 6);
  int lane = threadIdx.x & 63;
  if (row >= n) return;
  float2 acc = seg_gather_bf16(h2, off, cnt, ecv, row, lane);
  Lx2p[(size_t)row*64 + lane] = pack_bf16(acc.x, acc.y);
}

// -------- head s2 + classifier (s3 already computed inside mfma(h2)) --------
__global__ __launch_bounds__(64) void head_s2(const unsigned int* __restrict__ Lx2p,
                                              const float* __restrict__ sel3,
                                              const int* __restrict__ bidx,
                                              const float* __restrict__ weight,
                                              const float* __restrict__ c1w,
                                              const float* __restrict__ c1b,
                                              const float* __restrict__ cls,
                                              const float* __restrict__ clsb,
                                              float* __restrict__ out, int Bn){
  __shared__ float ssel[100];
  __shared__ float spre[5];
  int b = blockIdx.x, lane = threadIdx.x;
  float cw = (lane < 50) ? c1w[lane] : 0.f;
  int bi  = (lane < 50) ? bidx[(size_t)b*50 + lane] : 0;
  float gx = 0.f, gy = 0.f;
  const unsigned int* __restrict__ tp = Lx2p + lane;    // row stride 64 uints
  #pragma unroll
  for (int l = 0; l < 50; l += 5){
    int i0 = __shfl(bi, l+0), i1 = __shfl(bi, l+1), i2 = __shfl(bi, l+2);
    int i3 = __shfl(bi, l+3), i4 = __shfl(bi, l+4);
    float w0 = __shfl(cw, l+0), w1 = __shfl(cw, l+1), w2v = __shfl(cw, l+2);
    float w3 = __shfl(cw, l+3), w4 = __shfl(cw, l+4);
    unsigned int p0 = tp[(size_t)i0*64];
    unsigned int p1 = tp[(size_t)i1*64];
    unsigned int p2 = tp[(size_t)i2*64];
    unsigned int p3 = tp[(size_t)i3*64];
    unsigned int p4 = tp[(size_t)i4*64];
    gx = fmaf(w0, bf_lo(p0), gx); gy = fmaf(w0, bf_hi(p0), gy);
    gx = fmaf(w1, bf_lo(p1), gx); gy = fmaf(w1, bf_hi(p1), gy);
    gx = fmaf(w2v, bf_lo(p2), gx); gy = fmaf(w2v, bf_hi(p2), gy);
    gx = fmaf(w3, bf_lo(p3), gx); gy = fmaf(w3, bf_hi(p3), gy);
    gx = fmaf(w4, bf_lo(p4), gx); gy = fmaf(w4, bf_hi(p4), gy);
  }
  float s = 0.f;
  #pragma unroll 8
  for (int d = 0; d < 128; d += 2){
    float ge = __shfl(gx, d >> 1);
    float go = __shfl(gy, d >> 1);
    if (lane < 50){
      s = fmaf(ge, weight[d*50 + lane], s);
      s = fmaf(go, weight[(d+1)*50 + lane], s);
    }
  }
  if (lane < 50){
    float v = s + c1b[0];
    ssel[lane] = v;
    out[(size_t)Bn + (size_t)b*100 + lane] = v;
    ssel[50 + lane] = sel3[(size_t)b*50 + lane];
  }
  __syncthreads();
  if (lane < 5){
    float sc = clsb[lane];
    for (int j = 0; j < 100; ++j) sc = fmaf(ssel[j], cls[j*5 + lane], sc);
    spre[lane] = sc;
  }
  __syncthreads();
  if (lane == 0){
    int best = 0; float bv = spre[0];
    #pragma unroll
    for (int k = 1; k < 5; ++k) if (spre[k] > bv){ bv = spre[k]; best = k; }
    out[b] = (float)best;
  }
}

// ---------------------------------------------------------------------------
extern "C" void kernel_launch(void* const* d_in, const int* in_sizes, int n_in,
                              void* d_out, int out_size, void* d_ws, size_t ws_size,
                              hipStream_t stream) {
  const float* A1     = (const float*)d_in[0];
  const int*   rows   = (const int*)  d_in[1];
  const int*   cols   = (const int*)  d_in[2];
  const float* vals   = (const float*)d_in[3];
  const int*   bidx   = (const int*)  d_in[4];
  const float* raw_c  = (const float*)d_in[5];
  const float* nparam = (const float*)d_in[6];
  const float* Lin1   = (const float*)d_in[7];
  const float* Lin1_b = (const float*)d_in[8];
  const float* gc1_w  = (const float*)d_in[9];
  const float* gc1_b  = (const float*)d_in[10];
  const float* gc2_w  = (const float*)d_in[11];
  const float* gc2_b  = (const float*)d_in[12];
  const float* weight = (const float*)d_in[13];
  const float* weight2= (const float*)d_in[14];
  const float* c1w    = (const float*)d_in[15];
  const float* c1b    = (const float*)d_in[16];
  const float* c2w    = (const float*)d_in[17];
  const float* c2b    = (const float*)d_in[18];
  const float* cls    = (const float*)d_in[19];
  const float* clsb   = (const float*)d_in[20];

  int N  = in_sizes[0] / 129;
  int E  = in_sizes[1];
  int Bn = in_sizes[4] / 50;
  size_t NF = (size_t)N * 128;

  // workspace layout (region A: Lhi/Llo early, reused as packed Lx2 late)
  ushort_t* Lhi = (ushort_t*)d_ws;              // 2NF B
  ushort_t* Llo = Lhi + NF;                     // 2NF B
  unsigned int* Lx2p = (unsigned int*)d_ws;     // Lx2 packed bf16 (aliases Lhi/Llo)
  float*    S3  = (float*)(Llo + NF);           // loga1 fp32, 4NF B
  unsigned int* Hb   = (unsigned int*)(S3 + NF);  // h1/h2 bf16, 2NF B
  unsigned int* X1hi = Hb + NF/2;               // Lx1 hi, 2NF B
  unsigned int* X1lo = X1hi + NF/2;             // Lx1 lo, 2NF B
  ushort_t* Wb = (ushort_t*)(X1lo + NF/2);      // 6 x 16384 ushorts
  ushort_t* W1h = Wb,           *W1l = Wb + 16384;
  ushort_t* W2h = Wb + 2*16384, *W2l = Wb + 3*16384;
  ushort_t* W3h = Wb + 4*16384, *W3l = Wb + 5*16384;
  int* cnt    = (int*)(Wb + 6*16384);
  int* off    = cnt + N;
  int* rnk    = off + N;
  int* bsum   = rnk + E;
  int2* ecv   = (int2*)(bsum + 4096);
  float* uu3  = (float*)(ecv + E);
  float* sel3 = (float*)rnk;         // rnk dead after fill (K5); 819 KB << 6.4 MB

  int rowBlocks  = (N + 3) / 4;
  int G = (N + 256*SCAN_ITEMS - 1) / (256*SCAN_ITEMS);
  int mBlocks = 512;                 // 2 blocks/CU (64 KB LDS each)
  int nWaves  = mBlocks * 4;
  int epb = (((E + mBlocks - 1) / mBlocks) + 255) & ~255;   // edges/block, x256

  stage_a<<<(int)((N*32 + 255)/256), 256, 0, stream>>>(A1, Lhi, Llo, cnt,
                                                       Lin1_b, gc1_b, gc2_b, uu3, N);
  split_w3<<<192, 256, 0, stream>>>(Lin1, gc1_w, gc2_w, Wb);

  // loga1 = chain(L@Lin1[1:,:], lin1_b) -> S3 (fp32) ; wave 4: histogram
  mfma_chain<<<mBlocks, 320, 0, stream>>>(Lhi, Llo, W1h, W1l, Lin1_b, uu3, 0, raw_c,
                                          S3, (unsigned int*)nullptr, 0, N, nWaves,
                                          1, epb, E, rows, cols, vals, cnt, rnk, off, ecv,
                                          nullptr, nullptr, nullptr, nullptr, nullptr,
                                          nullptr, nullptr, 0);
  scan1<<<G, 256, 0, stream>>>(cnt, off, bsum, N);
  scan2<<<1, 256, 0, stream>>>(bsum, G);
  scan3<<<(N+255)/256, 256, 0, stream>>>(off, bsum, N);

  // h1 = chain(L@gc1_w[1:,:], gc1_b) -> Hb (bf16) ; wave 4: CSR fill
  mfma_chain<<<mBlocks, 320, 0, stream>>>(Lhi, Llo, W2h, W2l, gc1_b, uu3, 1, raw_c,
                                          (float*)nullptr, Hb, 1, N, nWaves,
                                          2, epb, E, rows, cols, vals, cnt, rnk, off, ecv,
                                          nullptr, nullptr, nullptr, nullptr, nullptr,
                                          nullptr, nullptr, 0);
  seg_x1<<<rowBlocks, 256, 0, stream>>>(Hb, off, cnt, ecv, S3, nparam, X1hi, X1lo, N);

  // h2 = chain(Lx1@gc2_w, gc2_b) -> Hb (bf16) ; waves 4-5: head s3 half
  mfma_chain<<<mBlocks, 384, 0, stream>>>((const ushort_t*)X1hi, (const ushort_t*)X1lo,
                                          W3h, W3l, gc2_b, uu3, 2, raw_c,
                                          (float*)nullptr, Hb, 1, N, nWaves,
                                          3, 0, 0, nullptr, nullptr, nullptr,
                                          nullptr, nullptr, nullptr, nullptr,
                                          S3, bidx, c2w, c2b, weight2, sel3,
                                          (float*)d_out, Bn);
  seg_x2<<<rowBlocks, 256, 0, stream>>>(Hb, off, cnt, ecv, Lx2p, N);  // packed Lx2
  head_s2<<<Bn, 64, 0, stream>>>(Lx2p, sel3, bidx, weight, c1w, c1b,
                                 cls, clsb, (float*)d_out, Bn);
}

// Round 2
// 576.308 us; speedup vs baseline: 1.2133x; 1.2133x over previous
//
#include <hip/hip_runtime.h>
#include <math.h>

// ---------------------------------------------------------------------------
// Hyperbolic GCN forward, fully collapsed (round-0 topology restored):
//  - logmap0(proj(expmap0(u))) == u ; bias chain is affine (At,Au per row)
//  - ALL GEMMs on matrix cores via split-bf16 (x = hi + lo, 3 MFMA passes).
//  - W (hi+lo, 64 KB) staged in LDS once per block; 512 persistent blocks.
//  - Round-1 lesson: wave-specialized fusion of scatter/atomic work starves
//    it of TLP (13 serial atomic round-trips/lane -> 150 us stragglers).
//    Scatter/atomic/gather kernels keep their own massive grids.
//  - This round: LDS XOR swizzle in mfma_chain (kills 3.67M 16-way bank
//    conflicts/dispatch), parallel scan2 (was 98 serial dependent loads),
//    packed-bf16 Lx2 (halves seg_x2 write + head s2 gather), vectorized
//    stage_a, single split_w3 launch.
// ---------------------------------------------------------------------------

typedef unsigned short ushort_t;
typedef __attribute__((ext_vector_type(8))) short short8;
typedef __attribute__((ext_vector_type(4))) float f32x4;
typedef __attribute__((ext_vector_type(4))) unsigned short u16x4;

__device__ __forceinline__ float wsum(float x){
  x += __shfl_xor(x, 32);
  x += __shfl_xor(x, 16);
  x += __shfl_xor(x, 8);
  x += __shfl_xor(x, 4);
  x += __shfl_xor(x, 2);
  x += __shfl_xor(x, 1);
  return x;
}

__device__ __forceinline__ void get_c(const float* rc, float& K, float& sK){
  float c = log1pf(expf(rc[0])) + 1e-5f;   // softplus(raw_c) + 1e-5
  K  = 1.0f / c;
  sK = sqrtf(K);
}

__device__ __forceinline__ float sinhx_over_x(float x){
  if (x > 1e-3f){
    float e  = __expf(x);
    float em = __builtin_amdgcn_rcpf(e);
    return 0.5f*(e - em) * __builtin_amdgcn_rcpf(x);
  }
  return 1.0f + x*x*(1.0f/6.0f);
}

__device__ __forceinline__ float facosh(float x){   // x >= 1+1e-7
  return __logf(x + sqrtf(fmaxf(fmaf(x, x, -1.0f), 0.0f)));
}

__device__ __forceinline__ ushort_t bf16_rne(float x){
  unsigned int u = __float_as_uint(x);
  u += 0x7fffu + ((u >> 16) & 1u);
  return (ushort_t)(u >> 16);
}
__device__ __forceinline__ float bf2f(ushort_t h){
  return __uint_as_float(((unsigned int)h) << 16);
}
__device__ __forceinline__ unsigned int pack_bf16(float x, float y){
  unsigned int bx = __float_as_uint(x);
  unsigned int by = __float_as_uint(y);
  bx = (bx + 0x7fffu + ((bx >> 16) & 1u)) >> 16;
  by = (by + 0x7fffu + ((by >> 16) & 1u)) & 0xffff0000u;
  return bx | by;
}
__device__ __forceinline__ float bf_lo(unsigned int p){ return __uint_as_float(p << 16); }
__device__ __forceinline__ float bf_hi(unsigned int p){ return __uint_as_float(p & 0xffff0000u); }

// Chain scalars: out_j = At*t_j + Au*u_j == logmap0(mobius_add(exp-chain)).
__device__ __forceinline__ void chain_scalars(float tt, float tu, float uu,
                                              float K, float sK,
                                              float& At, float& Au){
  float xn  = fmaxf(sqrtf(tt), 1e-15f);
  float th  = xn / sK;
  float f   = sinhx_over_x(th);
  float pn2 = f*f*tt;
  float p0  = sqrtf(fmaxf(K + pn2, 1e-7f));
  float S_yu = f * tu;
  float yn  = fmaxf(sqrtf(pn2), 1e-15f);
  float inv_yn = __builtin_amdgcn_rcpf(yn);
  float alpha = S_yu * inv_yn / sK;
  float coef  = alpha * (sK - p0);
  float cy  = coef * inv_yn;
  float cyf = cy * f;
  float pdw  = S_yu - cy*pn2;
  float spsq = uu - 2.f*cy*S_yu + cy*cy*pn2;
  float w0 = pdw / fmaxf(p0, 1e-7f);
  float md = spsq - w0*w0;
  float normu = fminf(sqrtf(fmaxf(md, 1e-7f)), 1e6f);
  float th2 = fmaxf(normu / sK, 1e-15f);
  float e  = __expf(th2);
  float em = __builtin_amdgcn_rcpf(e);
  float ch = 0.5f*(e + em);
  float g  = (th2 > 1e-3f) ? 0.5f*(e - em)*__builtin_amdgcn_rcpf(th2)
                           : 1.0f + th2*th2*(1.0f/6.0f);
  float rn2 = ch*ch*pn2 + 2.f*ch*g*pdw + g*g*spsq;
  float r0 = sqrtf(fmaxf(K + rn2, 1e-7f));
  float ynf = fmaxf(sqrtf(rn2), 1e-15f);
  float thf = fmaxf(r0/sK, 1.f+1e-7f);
  float rf = sK * facosh(thf) * __builtin_amdgcn_rcpf(ynf);
  At = rf*(ch*f - g*cyf);
  Au = rf*g;
}

// ---------- stage A: split A1[:,1:] into bf16 hi/lo (4 elems/thread) --------
__global__ __launch_bounds__(256) void stage_a(const float* __restrict__ A1,
                                               ushort_t* __restrict__ Lhi,
                                               ushort_t* __restrict__ Llo,
                                               int* __restrict__ cnt,
                                               const float* __restrict__ b0,
                                               const float* __restrict__ b1,
                                               const float* __restrict__ b2,
                                               float* __restrict__ uu3, int n){
  size_t i4 = (size_t)blockIdx.x * 256 + threadIdx.x;
  size_t tot4 = (size_t)n * 32;
  if (i4 < tot4){
    size_t row = i4 >> 5; int j0 = (int)(i4 & 31) * 4;
    const float* s = A1 + row*129 + 1 + j0;
    float v0 = s[0], v1 = s[1], v2 = s[2], v3 = s[3];
    ushort_t h0 = bf16_rne(v0), h1 = bf16_rne(v1), h2 = bf16_rne(v2), h3 = bf16_rne(v3);
    u16x4 hh = {h0, h1, h2, h3};
    u16x4 ll = {bf16_rne(v0 - bf2f(h0)), bf16_rne(v1 - bf2f(h1)),
                bf16_rne(v2 - bf2f(h2)), bf16_rne(v3 - bf2f(h3))};
    *(u16x4*)&Lhi[i4*4] = hh;
    *(u16x4*)&Llo[i4*4] = ll;
  }
  if (i4 < (size_t)n) cnt[i4] = 0;
  if (blockIdx.x == 0 && threadIdx.x < 64){
    int lane = threadIdx.x;
    const float* bs[3] = {b0, b1, b2};
    for (int k = 0; k < 3; ++k){
      float x = lane ? bs[k][2*lane] : 0.0f;
      float y = bs[k][2*lane+1];
      float s = wsum(x*x + y*y);
      if (lane == 0) uu3[k] = s;
    }
  }
}

// ---------- split+transpose all three 128x128 weights in one launch ---------
__global__ __launch_bounds__(256) void split_w3(const float* __restrict__ Lin1,
                                                const float* __restrict__ G1,
                                                const float* __restrict__ G2,
                                                ushort_t* __restrict__ Wb){
  int bid = blockIdx.x;           // 0..191
  int which = bid >> 6, b = bid & 63;
  const float* W = (which == 0) ? (Lin1 + 128) : (which == 1) ? (G1 + 128) : G2;
  ushort_t* Whi = Wb + (size_t)which * 2 * 16384;
  ushort_t* Wlo = Whi + 16384;
  int id = b * 256 + threadIdx.x;   // 0..16383
  int k = id >> 7, nn = id & 127;
  float v = W[(size_t)k*128 + nn];
  ushort_t h = bf16_rne(v);
  Whi[(size_t)nn*128 + k] = h;
  Wlo[(size_t)nn*128 + k] = bf16_rne(v - bf2f(h));
}

// ---------- MFMA GEMM (split-bf16 x3), W staged in LDS, grid-stride strips --
// Wave computes rows [m0, m0+16) x all 128 cols per strip. 16x16x32 bf16 MFMA.
// LDS XOR swizzle: Wt row n lives at ushort index (n*128+k) ^ ((n&7)<<3).
// Unswizzled, all 16 c-lanes of a quad read byte c*256+const -> same 4-bank
// group (16-way conflict, 3.67M/dispatch measured). Swizzled: 64 lanes spread
// uniformly over all 8 bank-quads (8 lanes each = b128 minimum).
__global__ __launch_bounds__(256) void mfma_chain(const ushort_t* __restrict__ Ahi,
                                                  const ushort_t* __restrict__ Alo,
                                                  const ushort_t* __restrict__ Whi,
                                                  const ushort_t* __restrict__ Wlo,
                                                  const float* __restrict__ bias,
                                                  const float* __restrict__ uu3, int uuidx,
                                                  const float* __restrict__ raw_c,
                                                  float* __restrict__ outF,
                                                  unsigned int* __restrict__ outH,
                                                  int mode, int n, int nWaves){
  __shared__ ushort_t Wsh[2][128*128];   // 64 KB: [0]=hi, [1]=lo, swizzled
  int tid = threadIdx.x;
  {
    const uint4* gh = (const uint4*)Whi;
    const uint4* gl = (const uint4*)Wlo;
    uint4* sh = (uint4*)Wsh[0];
    uint4* sl = (uint4*)Wsh[1];
    #pragma unroll
    for (int i = 0; i < 8; ++i){
      int idx = tid + 256*i;
      int sw = idx ^ ((idx >> 4) & 7);      // uint4-index swizzle == byte^((n&7)<<4)
      sh[sw] = gh[idx];
    }
    #pragma unroll
    for (int i = 0; i < 8; ++i){
      int idx = tid + 256*i;
      int sw = idx ^ ((idx >> 4) & 7);
      sl[sw] = gl[idx];
    }
  }
  __syncthreads();

  int lane = tid & 63;
  int c = lane & 15, quad = lane >> 4;
  int wid = blockIdx.x * 4 + (tid >> 6);
  int nStrips = (n + 15) >> 4;
  int csw = (c & 7) << 3;                   // ushort-index swizzle for reads

  float K, sK; get_c(raw_c, K, sK);
  float uu = uu3[uuidx];
  float uv[8];
  #pragma unroll
  for (int t = 0; t < 8; ++t){
    int col = t*16 + c;
    uv[t] = (col == 0) ? 0.f : bias[col];
  }

  for (int strip = wid; strip < nStrips; strip += nWaves){
    int m0 = strip * 16;
    int ra = m0 + c; if (ra > n - 1) ra = n - 1;
    short8 ahi[4], alo[4];
    #pragma unroll
    for (int kc = 0; kc < 4; ++kc){
      size_t aoff = (size_t)ra*128 + kc*32 + quad*8;
      ahi[kc] = *(const short8*)&Ahi[aoff];
      alo[kc] = *(const short8*)&Alo[aoff];
    }

    f32x4 acc[8];
    #pragma unroll
    for (int t = 0; t < 8; ++t){
      f32x4 z = {0.f, 0.f, 0.f, 0.f};
      acc[t] = z;
      int wrow = (t*16 + c) * 128;
      #pragma unroll
      for (int kc = 0; kc < 4; ++kc){
        int woff = (wrow + kc*32 + quad*8) ^ csw;
        short8 bhi = *(const short8*)&Wsh[0][woff];
        short8 blo = *(const short8*)&Wsh[1][woff];
        acc[t] = __builtin_amdgcn_mfma_f32_16x16x32_bf16(ahi[kc], bhi, acc[t], 0, 0, 0);
        acc[t] = __builtin_amdgcn_mfma_f32_16x16x32_bf16(ahi[kc], blo, acc[t], 0, 0, 0);
        acc[t] = __builtin_amdgcn_mfma_f32_16x16x32_bf16(alo[kc], bhi, acc[t], 0, 0, 0);
      }
    }

    if (c == 0){                     // output col 0 = time component, dropped
      f32x4 z = {0.f, 0.f, 0.f, 0.f};
      acc[0] = z;
    }
    #pragma unroll
    for (int r = 0; r < 4; ++r){
      float tt = 0.f, tu = 0.f;
      #pragma unroll
      for (int t = 0; t < 8; ++t){
        float v = acc[t][r];
        tt = fmaf(v, v, tt);
        tu = fmaf(v, uv[t], tu);
      }
      #pragma unroll
      for (int m = 1; m <= 8; m <<= 1){   // reduce across 16 lanes of the quad
        tt += __shfl_xor(tt, m);
        tu += __shfl_xor(tu, m);
      }
      float At, Au; chain_scalars(tt, tu, uu, K, sK, At, Au);
      int row = m0 + quad*4 + r;
      if (mode == 0){
        if (row < n){
          #pragma unroll
          for (int t = 0; t < 8; ++t){
            float o = fmaf(At, acc[t][r], Au*uv[t]);
            outF[(size_t)row*128 + t*16 + c] = o;
          }
        }
      } else {
        #pragma unroll
        for (int t = 0; t < 8; ++t){
          float o  = fmaf(At, acc[t][r], Au*uv[t]);
          float on = __shfl_xor(o, 1);
          if (row < n && !(c & 1))
            outH[(size_t)row*64 + t*8 + (c >> 1)] = pack_bf16(o, on);
        }
      }
    }
  }
}

// --------------------------- CSR build -------------------------------------
__global__ __launch_bounds__(256) void hist_k(const int* __restrict__ rows,
                                              int* __restrict__ cnt,
                                              int* __restrict__ rnk, int e){
  int base = (blockIdx.x * 256 + threadIdx.x) * 4;
  if (base + 3 < e){
    int4 r = *(const int4*)&rows[base];
    int k0 = atomicAdd(&cnt[r.x], 1);
    int k1 = atomicAdd(&cnt[r.y], 1);
    int k2 = atomicAdd(&cnt[r.z], 1);
    int k3 = atomicAdd(&cnt[r.w], 1);
    *(int4*)&rnk[base] = make_int4(k0, k1, k2, k3);
  } else {
    for (int i = base; i < e; ++i) rnk[i] = atomicAdd(&cnt[rows[i]], 1);
  }
}

#define SCAN_ITEMS 4
__global__ __launch_bounds__(256) void scan1(const int* __restrict__ cnt,
                                             int* __restrict__ off,
                                             int* __restrict__ bsum, int n){
  __shared__ int sh[256];
  int tid = threadIdx.x;
  int base = blockIdx.x * 256 * SCAN_ITEMS + tid * SCAN_ITEMS;
  int v[SCAN_ITEMS]; int s = 0;
  #pragma unroll
  for (int i = 0; i < SCAN_ITEMS; ++i){ int idx = base+i; v[i] = (idx < n) ? cnt[idx] : 0; s += v[i]; }
  sh[tid] = s; __syncthreads();
  for (int o = 1; o < 256; o <<= 1){
    int t = (tid >= o) ? sh[tid - o] : 0; __syncthreads();
    sh[tid] += t; __syncthreads();
  }
  int excl = sh[tid] - s;
  if (tid == 255) bsum[blockIdx.x] = sh[tid];
  int run = excl;
  #pragma unroll
  for (int i = 0; i < SCAN_ITEMS; ++i){ int idx = base+i; if (idx < n) off[idx] = run; run += v[i]; }
}

// parallel exclusive scan of block sums (G <= 256; G = ceil(N/1024) = 98)
__global__ __launch_bounds__(256) void scan2(int* __restrict__ bsum, int G){
  __shared__ int sh[256];
  int t = threadIdx.x;
  int v = (t < G) ? bsum[t] : 0;
  sh[t] = v; __syncthreads();
  for (int o = 1; o < 256; o <<= 1){
    int x = (t >= o) ? sh[t - o] : 0; __syncthreads();
    sh[t] += x; __syncthreads();
  }
  if (t < G) bsum[t] = sh[t] - v;
}

__global__ void scan3(int* __restrict__ off, const int* __restrict__ bsum, int n){
  int i = blockIdx.x * blockDim.x + threadIdx.x;
  if (i < n) off[i] += bsum[i / (256*SCAN_ITEMS)];
}

__global__ __launch_bounds__(256) void fill_k(const int* __restrict__ rows,
                                              const int* __restrict__ cols,
                                              const float* __restrict__ vals,
                                              const int* __restrict__ off,
                                              const int* __restrict__ rnk,
                                              int2* __restrict__ ecv, int e){
  int base = (blockIdx.x * 256 + threadIdx.x) * 4;
  if (base + 3 < e){
    int4   r = *(const int4*)&rows[base];
    int4   q = *(const int4*)&rnk[base];
    int4   c = *(const int4*)&cols[base];
    float4 v = *(const float4*)&vals[base];
    int o0 = off[r.x], o1 = off[r.y], o2 = off[r.z], o3 = off[r.w];
    ecv[o0 + q.x] = make_int2(c.x, __float_as_int(v.x));
    ecv[o1 + q.y] = make_int2(c.y, __float_as_int(v.y));
    ecv[o2 + q.z] = make_int2(c.z, __float_as_int(v.z));
    ecv[o3 + q.w] = make_int2(c.w, __float_as_int(v.w));
  } else {
    for (int i = base; i < e; ++i)
      ecv[off[rows[i]] + rnk[i]] = make_int2(cols[i], __float_as_int(vals[i]));
  }
}

// --------------------------- seg-sum (bf16 table, int2 edges) ---------------
__device__ __forceinline__ float2 seg_gather_bf16(const unsigned int* __restrict__ h,
                                                  const int* __restrict__ off,
                                                  const int* __restrict__ cnt,
                                                  const int2* __restrict__ ecv,
                                                  int row, int lane){
  float ax = 0.f, ay = 0.f, bx = 0.f, by = 0.f;
  int st = off[row], deg = cnt[row];
  const unsigned int* __restrict__ hb = h + lane;   // row stride = 64 uints
  for (int b = 0; b < deg; b += 64){
    int k = b + lane;
    int cc = 0; float vv = 0.f;
    if (k < deg){ int2 e = ecv[st+k]; cc = e.x; vv = __int_as_float(e.y); }
    int m = min(64, deg - b);
    for (int j = 0; j < m; j += 8){
      int   c0=__shfl(cc,j+0), c1=__shfl(cc,j+1), c2=__shfl(cc,j+2), c3=__shfl(cc,j+3);
      int   c4=__shfl(cc,j+4), c5=__shfl(cc,j+5), c6=__shfl(cc,j+6), c7=__shfl(cc,j+7);
      float v0=__shfl(vv,j+0), v1=__shfl(vv,j+1), v2=__shfl(vv,j+2), v3=__shfl(vv,j+3);
      float v4=__shfl(vv,j+4), v5=__shfl(vv,j+5), v6=__shfl(vv,j+6), v7=__shfl(vv,j+7);
      unsigned int p0 = hb[(size_t)c0*64];
      unsigned int p1 = hb[(size_t)c1*64];
      unsigned int p2 = hb[(size_t)c2*64];
      unsigned int p3 = hb[(size_t)c3*64];
      unsigned int p4 = hb[(size_t)c4*64];
      unsigned int p5 = hb[(size_t)c5*64];
      unsigned int p6 = hb[(size_t)c6*64];
      unsigned int p7 = hb[(size_t)c7*64];
      ax = fmaf(v0, bf_lo(p0), ax); ay = fmaf(v0, bf_hi(p0), ay);
      bx = fmaf(v1, bf_lo(p1), bx); by = fmaf(v1, bf_hi(p1), by);
      ax = fmaf(v2, bf_lo(p2), ax); ay = fmaf(v2, bf_hi(p2), ay);
      bx = fmaf(v3, bf_lo(p3), bx); by = fmaf(v3, bf_hi(p3), by);
      ax = fmaf(v4, bf_lo(p4), ax); ay = fmaf(v4, bf_hi(p4), ay);
      bx = fmaf(v5, bf_lo(p5), bx); by = fmaf(v5, bf_hi(p5), by);
      ax = fmaf(v6, bf_lo(p6), ax); ay = fmaf(v6, bf_hi(p6), ay);
      bx = fmaf(v7, bf_lo(p7), bx); by = fmaf(v7, bf_hi(p7), by);
    }
  }
  return make_float2(ax + bx, ay + by);
}

// ------ seg_x1: Lx1 = (1-n)*segsum(h1) + n*loga1 -> bf16 hi/lo split --------
__global__ __launch_bounds__(256) void seg_x1(const unsigned int* __restrict__ h1,
                                              const int* __restrict__ off,
                                              const int* __restrict__ cnt,
                                              const int2* __restrict__ ecv,
                                              const float* __restrict__ loga1,
                                              const float* __restrict__ nparam,
                                              unsigned int* __restrict__ X1hi,
                                              unsigned int* __restrict__ X1lo, int n){
  int row  = (int)((blockIdx.x * blockDim.x + threadIdx.x) >> 6);
  int lane = threadIdx.x & 63;
  if (row >= n) return;
  float2 acc = seg_gather_bf16(h1, off, cnt, ecv, row, lane);
  float nv = nparam[row];
  float2 la1 = *(const float2*)&loga1[(size_t)row*128 + 2*lane];
  float ox = (1.f-nv)*acc.x + nv*la1.x;
  float oy = (1.f-nv)*acc.y + nv*la1.y;
  unsigned int hp = pack_bf16(ox, oy);
  X1hi[(size_t)row*64 + lane] = hp;
  X1lo[(size_t)row*64 + lane] = pack_bf16(ox - bf_lo(hp), oy - bf_hi(hp));
}

// ------------------- seg_x2: Lx2 = segsum(h2)  (packed bf16 out) ------------
__global__ __launch_bounds__(256) void seg_x2(const unsigned int* __restrict__ h2,
                                              const int* __restrict__ off,
                                              const int* __restrict__ cnt,
                                              const int2* __restrict__ ecv,
                                              unsigned int* __restrict__ Lx2p, int n){
  int row  = (int)((blockIdx.x * blockDim.x + threadIdx.x) >> 6);
  int lane = threadIdx.x & 63;
  if (row >= n) return;
  float2 acc = seg_gather_bf16(h2, off, cnt, ecv, row, lane);
  Lx2p[(size_t)row*64 + lane] = pack_bf16(acc.x, acc.y);
}

// --------------------------- batch head -------------------------------------
// d<64: s2 gather from packed-bf16 Lx2; d>=64: s3 gather from fp32 loga1.
__global__ __launch_bounds__(128) void batch_head(const unsigned int* __restrict__ Lx2p,
                                                  const float* __restrict__ loga1,
                                                  const int* __restrict__ bidx,
                                                  const float* __restrict__ weight,
                                                  const float* __restrict__ weight2,
                                                  const float* __restrict__ c1w,
                                                  const float* __restrict__ c1b,
                                                  const float* __restrict__ c2w,
                                                  const float* __restrict__ c2b,
                                                  const float* __restrict__ cls,
                                                  const float* __restrict__ clsb,
                                                  float* __restrict__ out, int Bn){
  __shared__ float sg2[128], sg3[128], ssel[100], spre[5];
  __shared__ int sbi[50];
  __shared__ float sc1[50], sc2[50];
  int b = blockIdx.x, d = threadIdx.x;
  const int* bi = bidx + (size_t)b * 50;
  if (d < 50){ sbi[d] = bi[d]; sc1[d] = c1w[d]; sc2[d] = c2w[d]; }
  __syncthreads();
  int lane = d & 63;
  bool lo = d < 64;
  float gx = 0.f, gy = 0.f;
  if (lo){
    const unsigned int* __restrict__ tp = Lx2p + lane;   // row stride 64 uints
    #pragma unroll
    for (int l = 0; l < 50; l += 5){
      int i0 = sbi[l+0], i1 = sbi[l+1], i2 = sbi[l+2], i3 = sbi[l+3], i4 = sbi[l+4];
      unsigned int p0 = tp[(size_t)i0*64];
      unsigned int p1 = tp[(size_t)i1*64];
      unsigned int p2 = tp[(size_t)i2*64];
      unsigned int p3 = tp[(size_t)i3*64];
      unsigned int p4 = tp[(size_t)i4*64];
      float w0 = sc1[l+0], w1 = sc1[l+1], w2 = sc1[l+2], w3 = sc1[l+3], w4 = sc1[l+4];
      gx = fmaf(w0, bf_lo(p0), gx); gy = fmaf(w0, bf_hi(p0), gy);
      gx = fmaf(w1, bf_lo(p1), gx); gy = fmaf(w1, bf_hi(p1), gy);
      gx = fmaf(w2, bf_lo(p2), gx); gy = fmaf(w2, bf_hi(p2), gy);
      gx = fmaf(w3, bf_lo(p3), gx); gy = fmaf(w3, bf_hi(p3), gy);
      gx = fmaf(w4, bf_lo(p4), gx); gy = fmaf(w4, bf_hi(p4), gy);
    }
    sg2[2*lane] = gx; sg2[2*lane+1] = gy;
  } else {
    const float2* __restrict__ t2 = (const float2*)loga1 + lane;  // row stride 64
    #pragma unroll
    for (int l = 0; l < 50; l += 5){
      int i0 = sbi[l+0], i1 = sbi[l+1], i2 = sbi[l+2], i3 = sbi[l+3], i4 = sbi[l+4];
      float2 p0 = t2[(size_t)i0*64];
      float2 p1 = t2[(size_t)i1*64];
      float2 p2 = t2[(size_t)i2*64];
      float2 p3 = t2[(size_t)i3*64];
      float2 p4 = t2[(size_t)i4*64];
      float w0 = sc2[l+0], w1 = sc2[l+1], w2 = sc2[l+2], w3 = sc2[l+3], w4 = sc2[l+4];
      gx = fmaf(w0, p0.x, gx); gy = fmaf(w0, p0.y, gy);
      gx = fmaf(w1, p1.x, gx); gy = fmaf(w1, p1.y, gy);
      gx = fmaf(w2, p2.x, gx); gy = fmaf(w2, p2.y, gy);
      gx = fmaf(w3, p3.x, gx); gy = fmaf(w3, p3.y, gy);
      gx = fmaf(w4, p4.x, gx); gy = fmaf(w4, p4.y, gy);
    }
    sg3[2*lane] = gx; sg3[2*lane+1] = gy;
  }
  __syncthreads();
  if (d < 50){
    float s = 0.f;
    for (int k = 0; k < 128; ++k) s = fmaf(sg2[k], weight[k*50 + d], s);
    s += c1b[0];
    ssel[d] = s;
    out[(size_t)Bn + (size_t)b*100 + d] = s;
  } else if (d >= 64 && d < 114){
    int t = d - 64;
    float s = 0.f;
    for (int k = 0; k < 128; ++k) s = fmaf(sg3[k], weight2[k*50 + t], s);
    s += c2b[0];
    ssel[50 + t] = s;
    out[(size_t)Bn + (size_t)b*100 + 50 + t] = s;
  }
  __syncthreads();
  if (d < 5){
    float s = clsb[d];
    for (int j = 0; j < 100; ++j) s = fmaf(ssel[j], cls[j*5 + d], s);
    spre[d] = s;
  }
  __syncthreads();
  if (d == 0){
    int best = 0; float bv = spre[0];
    #pragma unroll
    for (int k = 1; k < 5; ++k) if (spre[k] > bv){ bv = spre[k]; best = k; }
    out[b] = (float)best;
  }
}

// ---------------------------------------------------------------------------
extern "C" void kernel_launch(void* const* d_in, const int* in_sizes, int n_in,
                              void* d_out, int out_size, void* d_ws, size_t ws_size,
                              hipStream_t stream) {
  const float* A1     = (const float*)d_in[0];
  const int*   rows   = (const int*)  d_in[1];
  const int*   cols   = (const int*)  d_in[2];
  const float* vals   = (const float*)d_in[3];
  const int*   bidx   = (const int*)  d_in[4];
  const float* raw_c  = (const float*)d_in[5];
  const float* nparam = (const float*)d_in[6];
  const float* Lin1   = (const float*)d_in[7];
  const float* Lin1_b = (const float*)d_in[8];
  const float* gc1_w  = (const float*)d_in[9];
  const float* gc1_b  = (const float*)d_in[10];
  const float* gc2_w  = (const float*)d_in[11];
  const float* gc2_b  = (const float*)d_in[12];
  const float* weight = (const float*)d_in[13];
  const float* weight2= (const float*)d_in[14];
  const float* c1w    = (const float*)d_in[15];
  const float* c1b    = (const float*)d_in[16];
  const float* c2w    = (const float*)d_in[17];
  const float* c2b    = (const float*)d_in[18];
  const float* cls    = (const float*)d_in[19];
  const float* clsb   = (const float*)d_in[20];

  int N  = in_sizes[0] / 129;
  int E  = in_sizes[1];
  int Bn = in_sizes[4] / 50;
  size_t NF = (size_t)N * 128;

  // workspace layout (region A: Lhi/Llo early, reused as packed Lx2 late)
  ushort_t* Lhi = (ushort_t*)d_ws;              // 2NF B
  ushort_t* Llo = Lhi + NF;                     // 2NF B
  unsigned int* Lx2p = (unsigned int*)d_ws;     // Lx2 packed bf16 (aliases Lhi/Llo)
  float*    S3  = (float*)(Llo + NF);           // loga1 fp32, 4NF B
  unsigned int* Hb   = (unsigned int*)(S3 + NF);  // h1/h2 bf16, 2NF B
  unsigned int* X1hi = Hb + NF/2;               // Lx1 hi, 2NF B
  unsigned int* X1lo = X1hi + NF/2;             // Lx1 lo, 2NF B
  ushort_t* Wb = (ushort_t*)(X1lo + NF/2);      // 6 x 16384 ushorts
  ushort_t* W1h = Wb,           *W1l = Wb + 16384;
  ushort_t* W2h = Wb + 2*16384, *W2l = Wb + 3*16384;
  ushort_t* W3h = Wb + 4*16384, *W3l = Wb + 5*16384;
  int* cnt    = (int*)(Wb + 6*16384);
  int* off    = cnt + N;
  int* rnk    = off + N;
  int* bsum   = rnk + E;
  int2* ecv   = (int2*)(bsum + 4096);
  float* uu3  = (float*)(ecv + E);

  int rowBlocks  = (N + 3) / 4;
  int G = (N + 256*SCAN_ITEMS - 1) / (256*SCAN_ITEMS);
  int eBlocks4 = (E/4 + 255) / 256 + 1;
  int mBlocks = 512;                 // 2 blocks/CU (64 KB LDS each)
  int nWaves  = mBlocks * 4;

  stage_a<<<(int)(((size_t)N*32 + 255)/256), 256, 0, stream>>>(A1, Lhi, Llo, cnt,
                                                     Lin1_b, gc1_b, gc2_b, uu3, N);
  split_w3<<<192, 256, 0, stream>>>(Lin1, gc1_w, gc2_w, Wb);

  hist_k<<<eBlocks4, 256, 0, stream>>>(rows, cnt, rnk, E);
  scan1<<<G, 256, 0, stream>>>(cnt, off, bsum, N);
  scan2<<<1, 256, 0, stream>>>(bsum, G);
  scan3<<<(N+255)/256, 256, 0, stream>>>(off, bsum, N);
  fill_k<<<eBlocks4, 256, 0, stream>>>(rows, cols, vals, off, rnk, ecv, E);

  // loga1 = chain(L@Lin1[1:,:], lin1_b) -> S3 (fp32)
  mfma_chain<<<mBlocks, 256, 0, stream>>>(Lhi, Llo, W1h, W1l, Lin1_b, uu3, 0, raw_c,
                                          S3, (unsigned int*)nullptr, 0, N, nWaves);
  // h1 = chain(L@gc1_w[1:,:], gc1_b) -> Hb (bf16)
  mfma_chain<<<mBlocks, 256, 0, stream>>>(Lhi, Llo, W2h, W2l, gc1_b, uu3, 1, raw_c,
                                          (float*)nullptr, Hb, 1, N, nWaves);
  seg_x1<<<rowBlocks, 256, 0, stream>>>(Hb, off, cnt, ecv, S3, nparam, X1hi, X1lo, N);
  // h2 = chain(Lx1@gc2_w, gc2_b) -> Hb (bf16)
  mfma_chain<<<mBlocks, 256, 0, stream>>>((const ushort_t*)X1hi, (const ushort_t*)X1lo,
                                          W3h, W3l, gc2_b, uu3, 2, raw_c,
                                          (float*)nullptr, Hb, 1, N, nWaves);
  seg_x2<<<rowBlocks, 256, 0, stream>>>(Hb, off, cnt, ecv, Lx2p, N);  // packed Lx2
  batch_head<<<Bn, 128, 0, stream>>>(Lx2p, S3, bidx, weight, weight2, c1w, c1b,
                                     c2w, c2b, cls, clsb, (float*)d_out, Bn);
}